// Round 6
// baseline (43491.330 us; speedup 1.0000x reference)
//
#include <hip/hip_runtime.h>

#define NB 128
#define TT 1024
#define DI 64
#define DH 512
#define DB 128
#define GZ 2048
#define KZ 576

typedef unsigned short u16;
typedef unsigned int u32;
typedef unsigned long long u64;

#if defined(__has_builtin)
#if __has_builtin(__builtin_amdgcn_fdot2)
#define HAS_FDOT2 1
#endif
#if __has_builtin(__builtin_amdgcn_sdot4)
#define HAS_SDOT4 1
#endif
#endif

typedef _Float16 half2v __attribute__((ext_vector_type(2)));

__device__ __forceinline__ float bf2f(u16 u) {
  union { u32 i; float f; } v; v.i = ((u32)u) << 16; return v.f;
}
__device__ __forceinline__ float fsig(float x) {
  return __builtin_amdgcn_rcpf(1.f + __expf(-x));
}
__device__ __forceinline__ float ftanh(float x) {
  return 1.f - 2.f * __builtin_amdgcn_rcpf(__expf(2.f * x) + 1.f);
}
__device__ __forceinline__ float dot2p(u32 w, u32 a, float acc) {
#ifdef HAS_FDOT2
  return __builtin_amdgcn_fdot2(__builtin_bit_cast(half2v, w),
                                __builtin_bit_cast(half2v, a), acc, false);
#else
  half2v hw = __builtin_bit_cast(half2v, w), ha = __builtin_bit_cast(half2v, a);
  acc = fmaf((float)hw.x, (float)ha.x, acc);
  return fmaf((float)hw.y, (float)ha.y, acc);
#endif
}
__device__ __forceinline__ int dot4i(u32 w, u32 a, int acc) {
#ifdef HAS_SDOT4
  return __builtin_amdgcn_sdot4((int)w, (int)a, acc, false);
#else
  acc += (((int)(w << 24)) >> 24) * (((int)(a << 24)) >> 24);
  acc += (((int)(w << 16)) >> 24) * (((int)(a << 16)) >> 24);
  acc += (((int)(w << 8))  >> 24) * (((int)(a << 8))  >> 24);
  acc += (((int)w) >> 24)         * (((int)a) >> 24);
  return acc;
#endif
}
__device__ __forceinline__ u32 packf16(float x, float y) {
  half2v h; h.x = (_Float16)x; h.y = (_Float16)y;
  return __builtin_bit_cast(u32, h);
}

// agent-scope exchange helpers (coherent across XCDs)
__device__ __forceinline__ void ex_store2(float* base, int idx, float a, float b) {
  union { float f[2]; u64 u; } v; v.f[0] = a; v.f[1] = b;
  __hip_atomic_store((u64*)(base + idx), v.u, __ATOMIC_RELAXED, __HIP_MEMORY_SCOPE_AGENT);
}
__device__ __forceinline__ float2 ex_load2(const float* base, int idx) {
  u64 u = __hip_atomic_load((u64*)(base + idx), __ATOMIC_RELAXED, __HIP_MEMORY_SCOPE_AGENT);
  union { u64 u; float f[2]; } v; v.u = u;
  return make_float2(v.f[0], v.f[1]);
}

// ---- ws layout (bytes, 256-aligned) ----
#define O_WZX  256                       // f16 pairs, x-part of Wz: 32*2048 u32
#define O_WZ8  (O_WZX + 262144)          // i8 quads, h-part of Wz: 128*2048 u32
#define O_SWZ  (O_WZ8 + 1048576)         // Wh scales (s/127^2): f32[2048]
#define O_BB8  (O_SWZ + 8192)            // bb i8 quads: 144*128 u32
#define O_SBB  (O_BB8 + 73728)           // bb weight scales: f32[128]
#define O_FF8  (O_SBB + 512)             // ff i8 quads: 4*32*512 u32
#define O_SFF  (O_FF8 + 262144)          // ff scales (w*Fq): f32[2048]
#define O_BIF  (O_SFF + 8192)            // bi f32[2048]
#define O_FFB  (O_BIF + 8192)            // ff biases f32[4*512]
#define O_BBBF (O_FFB + 8192)            // bbb f32[128]
#define O_HWP  (O_BBBF + 512)            // head pairs u32[512]
#define O_HBF  (O_HWP + 2048)            // hb f32[2]
#define O_EXZ  (O_HBF + 256)             // z exchange: 64 pairs x 2 halves x 2 parity x 2048 f32 = 2 MB
#define O_EXF  (O_EXZ + 2097152)         // ff exchange: same size = 2 MB
#define O_FLG  (O_EXF + 2097152)         // flags: 64 x 2 x 2 u32 (memset each launch)
#define WS_NEED ((u64)(O_FLG + 4096))    // ~5.9 MB

// ---------------- dtype detection (validated rounds 3-8) ----------------
__global__ void detect_kernel(const u16* x, const u16* wi, const u16* wh, int* flag) {
  const int l = threadIdx.x;
  int cnt = (((x[2 * l] >> 7) & 0xFF) < 134)
          + (((wi[2 * l] >> 7) & 0xFF) < 134)
          + (((wh[2 * l] >> 7) & 0xFF) < 134);
#pragma unroll
  for (int off = 32; off > 0; off >>= 1) cnt += __shfl_down(cnt, off, 64);
  if (l == 0) *flag = (cnt >= 180) ? 1 : 0;
}

__device__ __forceinline__ float ldf(int f, const void* s, u32 i) {
  return f ? bf2f(((const u16*)s)[i]) : ((const float*)s)[i];
}

// ---- prep: Wz x-part f16 pairs ----
__global__ void pwzx_kernel(const void* Wi, const int* __restrict__ flag,
                            u32* __restrict__ wzx) {
  const int o = blockIdx.x * 256 + threadIdx.x;
  const int k2 = blockIdx.y;
  const int f = *flag;
  const u32 i = (u32)o * DI + 2 * k2;
  wzx[(u32)k2 * GZ + o] = packf16(ldf(f, Wi, i), ldf(f, Wi, i + 1));
}

// ---- prep: Wz h-part -> i8 per-output-row scale (validated round 8) ----
__global__ void qwz_kernel(const void* Wh, const int* __restrict__ flag,
                           u32* __restrict__ wz8, float* __restrict__ swz) {
  const int o = blockIdx.x;
  const int l = threadIdx.x;
  const int f = *flag;
  float w[8]; float mx = 0.f;
#pragma unroll
  for (int qq = 0; qq < 2; ++qq) {
    const int q = l + 64 * qq;
#pragma unroll
    for (int e = 0; e < 4; ++e) {
      const float v = ldf(f, Wh, (u32)o * DH + 4 * q + e);
      w[qq * 4 + e] = v; mx = fmaxf(mx, fabsf(v));
    }
  }
#pragma unroll
  for (int off = 32; off > 0; off >>= 1) mx = fmaxf(mx, __shfl_xor(mx, off, 64));
  mx = fmaxf(mx, 1e-20f);
  const float inv = 127.f / mx;
  if (l == 0) swz[o] = mx / (127.f * 127.f);
#pragma unroll
  for (int qq = 0; qq < 2; ++qq) {
    const int q = l + 64 * qq;
    u32 p = 0;
#pragma unroll
    for (int e = 0; e < 4; ++e) {
      int b = (int)rintf(w[qq * 4 + e] * inv);
      b = b > 127 ? 127 : (b < -127 ? -127 : b);
      p |= ((u32)(b & 0xff)) << (8 * e);
    }
    wz8[(u32)q * GZ + o] = p;
  }
}

// ---- prep: backbone -> i8, per-output scale. block = output m, 64 threads ----
__global__ void qbb_kernel(const void* bb, const int* __restrict__ flag,
                           u32* __restrict__ bb8, float* __restrict__ sbb) {
  const int m = blockIdx.x;      // 0..127
  const int l = threadIdx.x;     // 0..63
  const int f = *flag;
  float mx = 0.f;
#pragma unroll
  for (int q = 0; q < 9; ++q)
    mx = fmaxf(mx, fabsf(ldf(f, bb, (u32)m * KZ + l + 64 * q)));
#pragma unroll
  for (int off = 32; off > 0; off >>= 1) mx = fmaxf(mx, __shfl_xor(mx, off, 64));
  mx = fmaxf(mx, 1e-20f);
  const float inv = 127.f / mx;
  if (l == 0) sbb[m] = mx / 127.f;   // weight dequant only; act scales applied in-kernel
  for (int k4 = l; k4 < 144; k4 += 64) {
    u32 p = 0;
#pragma unroll
    for (int e = 0; e < 4; ++e) {
      int b = (int)rintf(ldf(f, bb, (u32)m * KZ + 4 * k4 + e) * inv);
      b = b > 127 ? 127 : (b < -127 ? -127 : b);
      p |= ((u32)(b & 0xff)) << (8 * e);
    }
    bb8[(u32)k4 * DB + m] = p;
  }
}

// ---- prep: ff -> i8, per-(mat,output) scale folded with F-scale. block=(o,mat) ----
__global__ void qff_kernel(const void* f1, const void* f2, const void* ta,
                           const void* tb, const int* __restrict__ flag,
                           u32* __restrict__ ff8, float* __restrict__ sff) {
  const int o = blockIdx.x;      // 0..511
  const int mat = blockIdx.y;    // 0..3
  const int l = threadIdx.x;     // 0..31
  const void* s = (mat == 0) ? f1 : (mat == 1) ? f2 : (mat == 2) ? ta : tb;
  const int f = *flag;
  float w[4]; float mx = 0.f;
#pragma unroll
  for (int e = 0; e < 4; ++e) {
    w[e] = ldf(f, s, (u32)o * DB + 4 * l + e);
    mx = fmaxf(mx, fabsf(w[e]));
  }
#pragma unroll
  for (int off = 16; off > 0; off >>= 1) mx = fmaxf(mx, __shfl_xor(mx, off, 32));
  mx = fmaxf(mx, 1e-20f);
  const float inv = 127.f / mx;
  if (l == 0) sff[mat * DH + o] = (mx / 127.f) * (1.7159f / 127.f);  // w + F dequant
  u32 p = 0;
#pragma unroll
  for (int e = 0; e < 4; ++e) {
    int b = (int)rintf(w[e] * inv);
    b = b > 127 ? 127 : (b < -127 ? -127 : b);
    p |= ((u32)(b & 0xff)) << (8 * e);
  }
  ff8[((u32)mat * 32 + l) * DH + o] = p;
}

__global__ void psmall_kernel(const void* bi_s, const void* f1b_s, const void* f2b_s,
                              const void* tab_s, const void* tbb_s, const void* bbb_s,
                              const void* hw_s, const void* hb_s,
                              const int* __restrict__ flag,
                              float* __restrict__ bif, float* __restrict__ ffb,
                              float* __restrict__ bbbf, u32* __restrict__ hwp,
                              float* __restrict__ hbf) {
  const int f = *flag;
  for (int i = threadIdx.x; i < 2048; i += 1024) {
    bif[i] = ldf(f, bi_s, i);
    if (i < 512) {
      ffb[i]        = ldf(f, f1b_s, i);
      ffb[512 + i]  = ldf(f, f2b_s, i);
      ffb[1024 + i] = ldf(f, tab_s, i);
      ffb[1536 + i] = ldf(f, tbb_s, i);
      const int w = i >> 8, pr = i & 255;
      hwp[i] = packf16(ldf(f, hw_s, w * DH + 2 * pr), ldf(f, hw_s, w * DH + 2 * pr + 1));
    }
    if (i < 128) bbbf[i] = ldf(f, bbb_s, i);
    if (i < 2)   hbf[i] = ldf(f, hb_s, i);
  }
}

// ---- scan14 = scan13 + paired-CU weight-stream split ----
// 128 blocks: pair (p, p+64) same XCD (blockIdx%8 round-robin, m09).
// half 0 streams Wz rows 0..1023 (i,g gates) + ff1/ff2; half 1 streams rows
// 1024..2047 (f,o) + ta/tb. Per-CU weight stream halves (1.5MB -> 768KB/step).
// Both halves redundantly compute gates/bb/F/combine (bit-identical state).
// Two 8KB exchanges/step via agent-scope atomics, parity double-buffered;
// flags (seq=t+1) zeroed per launch by hipMemsetAsync.
__global__ __launch_bounds__(1024, 1)
void scan14(const void* __restrict__ xraw, const int* __restrict__ flagp,
            const u32* __restrict__ wzx, const u32* __restrict__ wz8,
            const float* __restrict__ swz,
            const u32* __restrict__ bb8, const float* __restrict__ sbb,
            const u32* __restrict__ ff8, const float* __restrict__ sff,
            const float* __restrict__ bif, const float* __restrict__ ffbv,
            const float* __restrict__ bbbf, const u32* __restrict__ hwp,
            const float* __restrict__ hbf,
            float* __restrict__ exz, float* __restrict__ exf,
            u32* __restrict__ flg, float* __restrict__ out)
{
  __shared__ __align__(16) u32   xf16q[64];        // x(t) f16 pairs [k2][row]
  __shared__ __align__(16) u32   ah8q[256];        // h(t-1) i8 quads [k4][row]
  __shared__ __align__(16) u32   hf16[512];        // h(t) f16 pairs [u][row]
  __shared__ __align__(16) u32   vcat8[288];       // [x|h_lstm] i8 quads
  __shared__ __align__(16) float sxq[2];
  __shared__ __align__(16) float zred[4 * 2 * 1024]; // 32 KB: 4 kslices x 2 rows x 1024 local outs
  __shared__ __align__(16) float zfl[2 * 1024];      // 8 KB: local z final [row][1024]
  __shared__ __align__(16) float bbred[8 * 2 * DB];
  __shared__ __align__(16) u32   Fq8[64];
  __shared__ __align__(16) float zffp[8 * 512];      // 16 KB raw ff partials [m2][fs][row][512]
  __shared__ __align__(16) float zffl[4 * 512];      // 8 KB scaled local ff [m2][row][512]
  __shared__ __align__(16) u32   bbL[144 * DB];      // 72 KB

  const int j = threadIdx.x;
  const int p = blockIdx.x & 63;       // pair id; rows 2p, 2p+1
  const int half = blockIdx.x >> 6;    // 0: i,g + ff1,ff2; 1: f,o + ta,tb
  const int obase = half << 10;        // Wz output base
  const int fbase = half << 1;         // ff mat base
  const int bf16in = *flagp;

  const int zs2 = j >> 8, zp2 = j & 255;        // Z: 4 kslices x 256 quad-groups
  const int bs = j >> 7, bm = j & 127;          // bb: 8 slices x 128 outputs
  const int ffs = j >> 9, fm2 = (j >> 8) & 1, ffp = j & 255; // ff: 2 kslices x 2 mats x 256 pairs
  const int grow = j >> 8, gup = j & 255;       // gates/combine (j<512)
  const int frow = j >> 6, fk2 = j & 63;        // F pack (j<128)
  const int hrow = j >> 7, hw_ = (j >> 6) & 1, hl = j & 63;  // head (j<256)

  float2 bgi, bgg, bgf, bgo, cbf1, cbf2, cbta, cbtb;
  float c0 = 0.f, c1 = 0.f;
  if (j < 512) {
    bgi  = *(const float2*)(bif  + 0 * DH + 2 * gup);
    bgg  = *(const float2*)(bif  + 1 * DH + 2 * gup);
    bgf  = *(const float2*)(bif  + 2 * DH + 2 * gup);
    bgo  = *(const float2*)(bif  + 3 * DH + 2 * gup);
    cbf1 = *(const float2*)(ffbv + 0 * DH + 2 * gup);
    cbf2 = *(const float2*)(ffbv + 1 * DH + 2 * gup);
    cbta = *(const float2*)(ffbv + 2 * DH + 2 * gup);
    cbtb = *(const float2*)(ffbv + 3 * DH + 2 * gup);
  }
  float bbr0 = 0.f, bbr1 = 0.f;
  if (j < 128) { bbr0 = bbbf[2 * fk2]; bbr1 = bbbf[2 * fk2 + 1]; }
  u32 hwreg[4]; float hbr = 0.f;
  if (half == 0 && j < 256) {
#pragma unroll
    for (int i = 0; i < 4; ++i) hwreg[i] = hwp[hw_ * 256 + hl + 64 * i];
    hbr = hbf[hw_];
  }
  const float4 zsc = *(const float4*)(swz + obase + 4 * zp2);  // Wh scales (local outs)
  const float sbbr = sbb[bm];
  float sfA = 0.f, sfB = 0.f;                   // ff2 scales (local mats)
  if (j < 512) {
    sfA = sff[(fbase + (j >> 8)) * DH + 2 * (j & 255)];
    sfB = sff[(fbase + (j >> 8)) * DH + 2 * (j & 255) + 1];
  }
  const float C127 = 1.f / 127.f;

  // exchange pointers (parity-dependent parts computed in loop)
  float* exzM0 = exz + (((p * 2 + half) * 2 + 0) << 11);
  float* exzM1 = exz + (((p * 2 + half) * 2 + 1) << 11);
  const float* exzP0 = exz + (((p * 2 + (half ^ 1)) * 2 + 0) << 11);
  const float* exzP1 = exz + (((p * 2 + (half ^ 1)) * 2 + 1) << 11);
  float* exfM0 = exf + (((p * 2 + half) * 2 + 0) << 11);
  float* exfM1 = exf + (((p * 2 + half) * 2 + 1) << 11);
  const float* exfP0 = exf + (((p * 2 + (half ^ 1)) * 2 + 0) << 11);
  const float* exfP1 = exf + (((p * 2 + (half ^ 1)) * 2 + 1) << 11);
  u32* fMine = flg + (p * 2 + half) * 2;
  u32* fPart = flg + (p * 2 + (half ^ 1)) * 2;

  // ---- bb weights resident in LDS (once) ----
  for (int i = j; i < 144 * DB; i += 1024) bbL[i] = bb8[i];

  // ---- preamble: h0 = 0; stage x(0) ----
  if (j < 512) { hf16[j] = 0u; if (j < 256) ah8q[j] = 0u; }
  if (j >= 512 && j < 576) {
    const int i = j - 512, xr = i >> 5, k2 = i & 31;
    const size_t xi = ((size_t)(2 * p + xr) * TT + 0) * 32 + k2;
    float a, bb_;
    if (bf16in) {
      const u32 w = ((const u32*)xraw)[xi];
      a = bf2f((u16)(w & 0xffffu)); bb_ = bf2f((u16)(w >> 16));
    } else {
      const float2 v = ((const float2*)xraw)[xi];
      a = v.x; bb_ = v.y;
    }
    xf16q[k2 * 2 + xr] = packf16(a, bb_);
    float m = fmaxf(fabsf(a), fabsf(bb_));
#pragma unroll
    for (int off = 16; off > 0; off >>= 1) m = fmaxf(m, __shfl_xor(m, off, 32));
    m = fmaxf(m, 1e-20f);
    if (k2 == 0) sxq[xr] = m * C127;
    const float inv = 127.f / m;
    const int q0 = (int)rintf(a * inv), q1 = (int)rintf(bb_ * inv);
    ((u16*)vcat8)[((k2 >> 1) * 2 + xr) * 2 + (k2 & 1)] =
        (u16)((q0 & 0xff) | ((q1 & 0xff) << 8));
  }
  __syncthreads();

  for (int t = 0; t < TT; ++t) {
    const int pb = t & 1;
    float* exzMine = pb ? exzM1 : exzM0;
    const float* exzPartB = pb ? exzP1 : exzP0;
    float* exfMine = pb ? exfM1 : exfM0;
    const float* exfPartB = pb ? exfP1 : exfP0;

    // ---- Z (local half): 4 k-slices x 256 quad-groups ----
    {
      float f0 = 0, f1 = 0, f2 = 0, f3 = 0, f4 = 0, f5 = 0, f6 = 0, f7 = 0;
      const u32* wpx = wzx + (size_t)(zs2 * 8) * GZ + obase + 4 * zp2;
      const uint2* xp = (const uint2*)xf16q + zs2 * 8;
#pragma unroll
      for (int k2 = 0; k2 < 8; ++k2) {
        const uint4 w = *(const uint4*)wpx; wpx += GZ;
        const uint2 a = xp[k2];
        f0 = dot2p(w.x, a.x, f0); f1 = dot2p(w.y, a.x, f1);
        f2 = dot2p(w.z, a.x, f2); f3 = dot2p(w.w, a.x, f3);
        f4 = dot2p(w.x, a.y, f4); f5 = dot2p(w.y, a.y, f5);
        f6 = dot2p(w.z, a.y, f6); f7 = dot2p(w.w, a.y, f7);
      }
      int i0 = 0, i1 = 0, i2 = 0, i3 = 0, i4 = 0, i5 = 0, i6 = 0, i7 = 0;
      const u32* wph = wz8 + (size_t)(zs2 * 32) * GZ + obase + 4 * zp2;
      const uint2* hp = (const uint2*)ah8q + zs2 * 32;
#pragma unroll 16
      for (int k4 = 0; k4 < 32; ++k4) {
        const uint4 w = *(const uint4*)wph; wph += GZ;
        const uint2 a = hp[k4];
        i0 = dot4i(w.x, a.x, i0); i1 = dot4i(w.y, a.x, i1);
        i2 = dot4i(w.z, a.x, i2); i3 = dot4i(w.w, a.x, i3);
        i4 = dot4i(w.x, a.y, i4); i5 = dot4i(w.y, a.y, i5);
        i6 = dot4i(w.z, a.y, i6); i7 = dot4i(w.w, a.y, i7);
      }
      *(float4*)(zred + (zs2 * 2 + 0) * 1024 + 4 * zp2) =
          make_float4(f0 + zsc.x * (float)i0, f1 + zsc.y * (float)i1,
                      f2 + zsc.z * (float)i2, f3 + zsc.w * (float)i3);
      *(float4*)(zred + (zs2 * 2 + 1) * 1024 + 4 * zp2) =
          make_float4(f4 + zsc.x * (float)i4, f5 + zsc.y * (float)i5,
                      f6 + zsc.z * (float)i6, f7 + zsc.w * (float)i7);
    }
    __syncthreads();                                   // (1) zred ready

    // ---- Z2: sum 4 slices -> zfl LDS + exchange write ----
    if (j < 512) {
      float2 r0 = make_float2(0.f, 0.f), r1 = make_float2(0.f, 0.f);
#pragma unroll
      for (int sl = 0; sl < 4; ++sl) {
        const float2 v0 = *(const float2*)(zred + (sl * 2 + 0) * 1024 + 2 * j);
        const float2 v1 = *(const float2*)(zred + (sl * 2 + 1) * 1024 + 2 * j);
        r0.x += v0.x; r0.y += v0.y; r1.x += v1.x; r1.y += v1.y;
      }
      *(float2*)(zfl + 2 * j) = r0;
      *(float2*)(zfl + 1024 + 2 * j) = r1;
      ex_store2(exzMine, 2 * j, r0.x, r0.y);
      ex_store2(exzMine, 1024 + 2 * j, r1.x, r1.y);
      __threadfence();
    }
    __syncthreads();                                   // (2) zfl + ex stores done
    if (j == 0) {
      __hip_atomic_store(fMine + 0, (u32)(t + 1), __ATOMIC_RELEASE, __HIP_MEMORY_SCOPE_AGENT);
      while (__hip_atomic_load(fPart + 0, __ATOMIC_RELAXED, __HIP_MEMORY_SCOPE_AGENT) < (u32)(t + 1)) {}
      (void)__hip_atomic_load(fPart + 0, __ATOMIC_ACQUIRE, __HIP_MEMORY_SCOPE_AGENT);
    }
    __syncthreads();                                   // (3) partner z ready

    // ---- LSTM gates (both halves, identical values); h_lstm -> vcat8 ----
    if (j < 512) {
      float2 Lv0 = *(const float2*)(zfl + grow * 1024 + 2 * gup);
      float2 Lv1 = *(const float2*)(zfl + grow * 1024 + 512 + 2 * gup);
      float2 Pv0 = ex_load2(exzPartB, grow * 1024 + 2 * gup);
      float2 Pv1 = ex_load2(exzPartB, grow * 1024 + 512 + 2 * gup);
      float2 zi, zg, zf, zo;
      if (half == 0) {
        zi = make_float2(bgi.x + Lv0.x, bgi.y + Lv0.y);
        zg = make_float2(bgg.x + Lv1.x, bgg.y + Lv1.y);
        zf = make_float2(bgf.x + Pv0.x, bgf.y + Pv0.y);
        zo = make_float2(bgo.x + Pv1.x, bgo.y + Pv1.y);
      } else {
        zi = make_float2(bgi.x + Pv0.x, bgi.y + Pv0.y);
        zg = make_float2(bgg.x + Pv1.x, bgg.y + Pv1.y);
        zf = make_float2(bgf.x + Lv0.x, bgf.y + Lv0.y);
        zo = make_float2(bgo.x + Lv1.x, bgo.y + Lv1.y);
      }
      c0 = fmaf(c0, fsig(zf.x + 1.f), ftanh(zi.x) * fsig(zg.x));
      c1 = fmaf(c1, fsig(zf.y + 1.f), ftanh(zi.y) * fsig(zg.y));
      const float hl0 = ftanh(c0) * fsig(zo.x);
      const float hl1 = ftanh(c1) * fsig(zo.y);
      const int q0 = (int)rintf(hl0 * 127.f), q1 = (int)rintf(hl1 * 127.f);
      ((u16*)vcat8)[((16 + (gup >> 1)) * 2 + grow) * 2 + (gup & 1)] =
          (u16)((q0 & 0xff) | ((q1 & 0xff) << 8));
    }
    __syncthreads();                                   // (4) h_lstm ready

    // ---- backbone partials: i8 sdot4 from LDS-resident weights ----
    {
      int ax0 = 0, ax1 = 0, ah0 = 0, ah1 = 0;
      const u32* bpL = bbL + (size_t)(bs * 18) * DB + bm;
      const uint2* vp = (const uint2*)vcat8 + bs * 18;
#pragma unroll
      for (int q = 0; q < 18; ++q) {
        const u32 w = bpL[(size_t)q * DB];
        const uint2 a = vp[q];
        if (bs * 18 + q < 16) {
          ax0 = dot4i(w, a.x, ax0); ax1 = dot4i(w, a.y, ax1);
        } else {
          ah0 = dot4i(w, a.x, ah0); ah1 = dot4i(w, a.y, ah1);
        }
      }
      const float sx0 = sxq[0], sx1 = sxq[1];
      bbred[(bs * 2 + 0) * DB + bm] = sbbr * (sx0 * (float)ax0 + C127 * (float)ah0);
      bbred[(bs * 2 + 1) * DB + bm] = sbbr * (sx1 * (float)ax1 + C127 * (float)ah1);
    }
    __syncthreads();                                   // (5) bb partials

    // ---- F reduce + lecun_tanh -> i8 quads ----
    if (j < 128) {
      float r0 = bbr0, r1 = bbr1;
#pragma unroll
      for (int sl = 0; sl < 8; ++sl) {
        const float2 v = *(const float2*)(bbred + (sl * 2 + frow) * DB + 2 * fk2);
        r0 += v.x; r1 += v.y;
      }
      const float F0 = 1.7159f * ftanh(0.666f * r0);
      const float F1 = 1.7159f * ftanh(0.666f * r1);
      const int q0 = (int)rintf(F0 * (127.f / 1.7159f));
      const int q1 = (int)rintf(F1 * (127.f / 1.7159f));
      ((u16*)Fq8)[((fk2 >> 1) * 2 + frow) * 2 + (fk2 & 1)] =
          (u16)((q0 & 0xff) | ((q1 & 0xff) << 8));
    }
    __syncthreads();                                   // (6) F ready

    // ---- ff (local 2 mats), 2 k-slices: raw int partials -> zffp ----
    {
      int a00 = 0, a01 = 0, a10 = 0, a11 = 0;
      const u32* fpw = ff8 + (size_t)((fbase + fm2) * 32 + ffs * 16) * DH + 2 * ffp;
      const uint2* Fp = (const uint2*)Fq8 + ffs * 16;
#pragma unroll 8
      for (int k4 = 0; k4 < 16; ++k4) {
        const uint2 w = *(const uint2*)fpw; fpw += DH;
        const uint2 a = Fp[k4];
        a00 = dot4i(w.x, a.x, a00); a01 = dot4i(w.x, a.y, a01);
        a10 = dot4i(w.y, a.x, a10); a11 = dot4i(w.y, a.y, a11);
      }
      const int base = (fm2 * 2 + ffs) * 2;
      *(float2*)(zffp + (base + 0) * 512 + 2 * ffp) = make_float2((float)a00, (float)a10);
      *(float2*)(zffp + (base + 1) * 512 + 2 * ffp) = make_float2((float)a01, (float)a11);
    }
    __syncthreads();                                   // (7) ff partials

    // ---- ff2: sum k-slices, scale, -> zffl LDS + exchange ----
    if (j < 512) {
      const int m2 = j >> 8, fp2 = j & 255;
      const float2 p00 = *(const float2*)(zffp + ((m2 * 2 + 0) * 2 + 0) * 512 + 2 * fp2);
      const float2 p10 = *(const float2*)(zffp + ((m2 * 2 + 1) * 2 + 0) * 512 + 2 * fp2);
      const float2 p01 = *(const float2*)(zffp + ((m2 * 2 + 0) * 2 + 1) * 512 + 2 * fp2);
      const float2 p11 = *(const float2*)(zffp + ((m2 * 2 + 1) * 2 + 1) * 512 + 2 * fp2);
      const float o0r0 = sfA * (p00.x + p10.x), o1r0 = sfB * (p00.y + p10.y);
      const float o0r1 = sfA * (p01.x + p11.x), o1r1 = sfB * (p01.y + p11.y);
      *(float2*)(zffl + (m2 * 2 + 0) * 512 + 2 * fp2) = make_float2(o0r0, o1r0);
      *(float2*)(zffl + (m2 * 2 + 1) * 512 + 2 * fp2) = make_float2(o0r1, o1r1);
      ex_store2(exfMine, (m2 * 2 + 0) * 512 + 2 * fp2, o0r0, o1r0);
      ex_store2(exfMine, (m2 * 2 + 1) * 512 + 2 * fp2, o0r1, o1r1);
      __threadfence();
    }
    __syncthreads();                                   // (8) zffl + ex stores done
    if (j == 0) {
      __hip_atomic_store(fMine + 1, (u32)(t + 1), __ATOMIC_RELEASE, __HIP_MEMORY_SCOPE_AGENT);
      while (__hip_atomic_load(fPart + 1, __ATOMIC_RELAXED, __HIP_MEMORY_SCOPE_AGENT) < (u32)(t + 1)) {}
      (void)__hip_atomic_load(fPart + 1, __ATOMIC_ACQUIRE, __HIP_MEMORY_SCOPE_AGENT);
    }
    __syncthreads();                                   // (9) partner ff ready

    // ---- combine -> h_new || stage x(t+1) ----
    if (j < 512) {
      float2 v1, v2, va, vb;
      const float2 L0 = *(const float2*)(zffl + (0 * 2 + grow) * 512 + 2 * gup);
      const float2 L1 = *(const float2*)(zffl + (1 * 2 + grow) * 512 + 2 * gup);
      const float2 P0 = ex_load2(exfPartB, (0 * 2 + grow) * 512 + 2 * gup);
      const float2 P1 = ex_load2(exfPartB, (1 * 2 + grow) * 512 + 2 * gup);
      if (half == 0) { v1 = L0; v2 = L1; va = P0; vb = P1; }
      else           { v1 = P0; v2 = P1; va = L0; vb = L1; }
      const float z1x = v1.x + cbf1.x, z1y = v1.y + cbf1.y;
      const float z2x = v2.x + cbf2.x, z2y = v2.y + cbf2.y;
      const float zax = va.x + cbta.x, zay = va.y + cbta.y;
      const float zbx = vb.x + cbtb.x, zby = vb.y + cbtb.y;
      const float ti0 = fsig(zax + zbx), ti1 = fsig(zay + zby);
      const float hn0 = fmaf(ftanh(z1x), 1.f - ti0, ti0 * ftanh(z2x));
      const float hn1 = fmaf(ftanh(z1y), 1.f - ti1, ti1 * ftanh(z2y));
      hf16[gup * 2 + grow] = packf16(hn0, hn1);
      const int q0 = (int)rintf(hn0 * 127.f), q1 = (int)rintf(hn1 * 127.f);
      ((u16*)ah8q)[((gup >> 1) * 2 + grow) * 2 + (gup & 1)] =
          (u16)((q0 & 0xff) | ((q1 & 0xff) << 8));
      if (t == TT - 1 && half == 0) {
        float* lp = out + (size_t)NB * TT * 2 + (size_t)(2 * p + grow) * DH + 2 * gup;
        lp[0] = hn0; lp[1] = hn1;
      }
    } else if (j < 576 && t + 1 < TT) {
      const int i = j - 512, xr = i >> 5, k2 = i & 31;
      const size_t xi = ((size_t)(2 * p + xr) * TT + (t + 1)) * 32 + k2;
      float a, bb_;
      if (bf16in) {
        const u32 w = ((const u32*)xraw)[xi];
        a = bf2f((u16)(w & 0xffffu)); bb_ = bf2f((u16)(w >> 16));
      } else {
        const float2 v = ((const float2*)xraw)[xi];
        a = v.x; bb_ = v.y;
      }
      xf16q[k2 * 2 + xr] = packf16(a, bb_);
      float m = fmaxf(fabsf(a), fabsf(bb_));
#pragma unroll
      for (int off = 16; off > 0; off >>= 1) m = fmaxf(m, __shfl_xor(m, off, 32));
      m = fmaxf(m, 1e-20f);
      if (k2 == 0) sxq[xr] = m * C127;
      const float inv = 127.f / m;
      const int q0 = (int)rintf(a * inv), q1 = (int)rintf(bb_ * inv);
      ((u16*)vcat8)[((k2 >> 1) * 2 + xr) * 2 + (k2 & 1)] =
          (u16)((q0 & 0xff) | ((q1 & 0xff) << 8));
    }
    __syncthreads();                                   // (10) h_new + x(t+1) ready

    // ---- head: half 0 only, in the shadow of next Z ----
    if (half == 0 && j < 256) {
      float acc = 0.f;
#pragma unroll
      for (int i = 0; i < 4; ++i)
        acc = dot2p(hwreg[i], hf16[(hl + 64 * i) * 2 + hrow], acc);
#pragma unroll
      for (int off = 32; off > 0; off >>= 1) acc += __shfl_down(acc, off, 64);
      if (hl == 0) out[((size_t)(2 * p + hrow) * TT + t) * 2 + hw_] = acc + hbr;
    }
  }
}

// ---------------- fallback (round-3 verified, bf16 d_in, small ws) ----------------
__device__ __forceinline__ void fma8(float& acc, const uint4 u, const float* v) {
  union { u32 i; float f; } tt;
  tt.i = u.x << 16;          acc = fmaf(tt.f, v[0], acc);
  tt.i = u.x & 0xffff0000u;  acc = fmaf(tt.f, v[1], acc);
  tt.i = u.y << 16;          acc = fmaf(tt.f, v[2], acc);
  tt.i = u.y & 0xffff0000u;  acc = fmaf(tt.f, v[3], acc);
  tt.i = u.z << 16;          acc = fmaf(tt.f, v[4], acc);
  tt.i = u.z & 0xffff0000u;  acc = fmaf(tt.f, v[5], acc);
  tt.i = u.w << 16;          acc = fmaf(tt.f, v[6], acc);
  tt.i = u.w & 0xffff0000u;  acc = fmaf(tt.f, v[7], acc);
}
__global__ __launch_bounds__(256, 1)
void fb_scan(const u16* __restrict__ x,   const u16* __restrict__ Wi,
             const u16* __restrict__ bi,  const u16* __restrict__ Wh,
             const u16* __restrict__ bbW, const u16* __restrict__ bbb,
             const u16* __restrict__ f1W, const u16* __restrict__ f1b,
             const u16* __restrict__ f2W, const u16* __restrict__ f2b,
             const u16* __restrict__ taW, const u16* __restrict__ tab,
             const u16* __restrict__ tbW, const u16* __restrict__ tbb,
             const u16* __restrict__ hW,  const u16* __restrict__ hb,
             float* __restrict__ out)
{
  __shared__ __align__(16) float vcat[DI + DH];
  __shared__ __align__(16) float Fb2[DB];
  __shared__ __align__(16) float fpart[256];
  __shared__ __align__(16) float hprev[DH];
  const int j = threadIdx.x, b = blockIdx.x;
  const int u0 = j, u1 = j + 256;
  float bi_r[8];
#pragma unroll
  for (int k = 0; k < 8; ++k) bi_r[k] = bf2f(bi[j + 256 * k]);
  const float b_f1_0 = bf2f(f1b[u0]), b_f1_1 = bf2f(f1b[u1]);
  const float b_f2_0 = bf2f(f2b[u0]), b_f2_1 = bf2f(f2b[u1]);
  const float b_ta_0 = bf2f(tab[u0]), b_ta_1 = bf2f(tab[u1]);
  const float b_tb_0 = bf2f(tbb[u0]), b_tb_1 = bf2f(tbb[u1]);
  const float b_bb = (j < DB) ? bf2f(bbb[j]) : 0.f;
  float hwr[8]; float hbr = 0.f;
  if (j < 128) {
    const int w = j >> 6, l = j & 63;
#pragma unroll
    for (int q = 0; q < 8; ++q) hwr[q] = bf2f(hW[w * DH + q * 64 + l]);
    hbr = bf2f(hb[w]);
  }
  float c0 = 0.f, c1 = 0.f;
  hprev[u0] = 0.f; hprev[u1] = 0.f;
  const u16* xp = x + (size_t)b * TT * DI;
  __syncthreads();
  for (int t = 0; t < TT; ++t) {
    if (j < DI) vcat[j] = bf2f(xp[t * DI + j]);
    __syncthreads();
    float a[8];
#pragma unroll
    for (int k = 0; k < 8; ++k) a[k] = bi_r[k];
#pragma unroll
    for (int r = 0; r < 8; ++r) {
      const u16* wr = Wi + ((size_t)(j + 256 * r)) * DI;
      float acc = a[r];
#pragma unroll
      for (int kk = 0; kk < DI; kk += 8) fma8(acc, *(const uint4*)(wr + kk), vcat + kk);
      a[r] = acc;
    }
#pragma unroll 1
    for (int kb = 0; kb < DH; kb += 64) {
      float hreg[64];
#pragma unroll
      for (int q = 0; q < 16; ++q)
        *(float4*)(hreg + 4 * q) = *(const float4*)(hprev + kb + 4 * q);
#pragma unroll
      for (int r = 0; r < 8; ++r) {
        const u16* wr = Wh + ((size_t)(j + 256 * r)) * DH + kb;
        float acc = a[r];
#pragma unroll
        for (int cc = 0; cc < 8; ++cc) fma8(acc, *(const uint4*)(wr + 8 * cc), hreg + 8 * cc);
        a[r] = acc;
      }
    }
    {
      const float cn0 = fmaf(c0, fsig(a[4] + 1.f), ftanh(a[0]) * fsig(a[2]));
      const float cn1 = fmaf(c1, fsig(a[5] + 1.f), ftanh(a[1]) * fsig(a[3]));
      c0 = cn0; c1 = cn1;
      vcat[DI + u0] = ftanh(cn0) * fsig(a[6]);
      vcat[DI + u1] = ftanh(cn1) * fsig(a[7]);
    }
    __syncthreads();
    {
      const int mm = j & (DB - 1), pp = j >> 7;
      const u16* br = bbW + (size_t)mm * KZ + pp * 288;
      const float* vs = vcat + pp * 288;
      float s0 = 0.f, s1 = 0.f, s2v = 0.f, s3 = 0.f;
#pragma unroll
      for (int kk = 0; kk < 288; kk += 32) {
        fma8(s0, *(const uint4*)(br + kk), vs + kk);
        fma8(s1, *(const uint4*)(br + kk + 8), vs + kk + 8);
        fma8(s2v, *(const uint4*)(br + kk + 16), vs + kk + 16);
        fma8(s3, *(const uint4*)(br + kk + 24), vs + kk + 24);
      }
      fpart[j] = (s0 + s1) + (s2v + s3);
    }
    __syncthreads();
    if (j < DB) Fb2[j] = 1.7159f * ftanh(0.666f * (b_bb + fpart[j] + fpart[j + DB]));
    __syncthreads();
    {
      float Fr[DB];
#pragma unroll
      for (int q = 0; q < 32; ++q) *(float4*)(Fr + 4 * q) = *(const float4*)(Fb2 + 4 * q);
      const u16* rp[8] = {
        f1W + (size_t)u0 * DB, f1W + (size_t)u1 * DB,
        f2W + (size_t)u0 * DB, f2W + (size_t)u1 * DB,
        taW + (size_t)u0 * DB, taW + (size_t)u1 * DB,
        tbW + (size_t)u0 * DB, tbW + (size_t)u1 * DB };
      float sacc[8] = { b_f1_0, b_f1_1, b_f2_0, b_f2_1, b_ta_0, b_ta_1, b_tb_0, b_tb_1 };
#pragma unroll
      for (int rr = 0; rr < 8; ++rr) {
        float acc = sacc[rr];
        const u16* r = rp[rr];
#pragma unroll
        for (int kk = 0; kk < DB; kk += 8) fma8(acc, *(const uint4*)(r + kk), Fr + kk);
        sacc[rr] = acc;
      }
      const float ti0 = fsig(sacc[4] + sacc[6]);
      const float ti1 = fsig(sacc[5] + sacc[7]);
      hprev[u0] = fmaf(ftanh(sacc[0]), 1.f - ti0, ti0 * ftanh(sacc[2]));
      hprev[u1] = fmaf(ftanh(sacc[1]), 1.f - ti1, ti1 * ftanh(sacc[3]));
    }
    __syncthreads();
    if (j < 128) {
      const int l = j & 63;
      float acc = 0.f;
#pragma unroll
      for (int q = 0; q < 8; ++q) acc = fmaf(hprev[q * 64 + l], hwr[q], acc);
#pragma unroll
      for (int off = 32; off > 0; off >>= 1) acc += __shfl_down(acc, off, 64);
      if (l == 0) out[((size_t)b * TT + t) * 2 + (j >> 6)] = acc + hbr;
    }
  }
  out[(size_t)NB * TT * 2 + (size_t)b * DH + u0] = hprev[u0];
  out[(size_t)NB * TT * 2 + (size_t)b * DH + u1] = hprev[u1];
}

extern "C" void kernel_launch(void* const* d_in, const int* in_sizes, int n_in,
                              void* d_out, int out_size, void* d_ws, size_t ws_size,
                              hipStream_t stream) {
  (void)in_sizes; (void)n_in; (void)out_size;

  if (ws_size >= WS_NEED) {
    char* ws = (char*)d_ws;
    int* flag = (int*)ws;
    detect_kernel<<<dim3(1), dim3(64), 0, stream>>>(
        (const u16*)d_in[0], (const u16*)d_in[1], (const u16*)d_in[3], flag);
    pwzx_kernel<<<dim3(8, 32), dim3(256), 0, stream>>>(d_in[1], flag, (u32*)(ws + O_WZX));
    qwz_kernel<<<dim3(2048), dim3(64), 0, stream>>>(d_in[3], flag,
                                                    (u32*)(ws + O_WZ8), (float*)(ws + O_SWZ));
    qbb_kernel<<<dim3(128), dim3(64), 0, stream>>>(d_in[4], flag,
                                                   (u32*)(ws + O_BB8), (float*)(ws + O_SBB));
    qff_kernel<<<dim3(512, 4), dim3(32), 0, stream>>>(d_in[6], d_in[8], d_in[10],
                                                      d_in[12], flag,
                                                      (u32*)(ws + O_FF8), (float*)(ws + O_SFF));
    psmall_kernel<<<dim3(1), dim3(1024), 0, stream>>>(
        d_in[2], d_in[7], d_in[9], d_in[11], d_in[13], d_in[5], d_in[14], d_in[15],
        flag, (float*)(ws + O_BIF), (float*)(ws + O_FFB), (float*)(ws + O_BBBF),
        (u32*)(ws + O_HWP), (float*)(ws + O_HBF));

    hipMemsetAsync(ws + O_FLG, 0, 4096, stream);   // zero pair flags each launch

    scan14<<<dim3(128), dim3(1024), 0, stream>>>(
        d_in[0], flag,
        (const u32*)(ws + O_WZX), (const u32*)(ws + O_WZ8), (const float*)(ws + O_SWZ),
        (const u32*)(ws + O_BB8), (const float*)(ws + O_SBB),
        (const u32*)(ws + O_FF8), (const float*)(ws + O_SFF),
        (const float*)(ws + O_BIF), (const float*)(ws + O_FFB),
        (const float*)(ws + O_BBBF), (const u32*)(ws + O_HWP),
        (const float*)(ws + O_HBF),
        (float*)(ws + O_EXZ), (float*)(ws + O_EXF), (u32*)(ws + O_FLG),
        (float*)d_out);
  } else {
    fb_scan<<<dim3(NB), dim3(256), 0, stream>>>(
        (const u16*)d_in[0],  (const u16*)d_in[1],  (const u16*)d_in[2],
        (const u16*)d_in[3],  (const u16*)d_in[4],  (const u16*)d_in[5],
        (const u16*)d_in[6],  (const u16*)d_in[7],  (const u16*)d_in[8],
        (const u16*)d_in[9],  (const u16*)d_in[10], (const u16*)d_in[11],
        (const u16*)d_in[12], (const u16*)d_in[13], (const u16*)d_in[14],
        (const u16*)d_in[15], (float*)d_out);
  }
}

// Round 7
// 15378.990 us; speedup vs baseline: 2.8280x; 2.8280x over previous
//
#include <hip/hip_runtime.h>

#define NB 128
#define TT 1024
#define DI 64
#define DH 512
#define DB 128
#define GZ 2048
#define KZ 576

typedef unsigned short u16;
typedef unsigned char u8;
typedef unsigned int u32;
typedef unsigned long long u64;

#if defined(__has_builtin)
#if __has_builtin(__builtin_amdgcn_fdot2)
#define HAS_FDOT2 1
#endif
#if __has_builtin(__builtin_amdgcn_sdot4)
#define HAS_SDOT4 1
#endif
#endif

typedef _Float16 half2v __attribute__((ext_vector_type(2)));

__device__ __forceinline__ float bf2f(u16 u) {
  union { u32 i; float f; } v; v.i = ((u32)u) << 16; return v.f;
}
__device__ __forceinline__ float fsig(float x) {
  return __builtin_amdgcn_rcpf(1.f + __expf(-x));
}
__device__ __forceinline__ float ftanh(float x) {
  return 1.f - 2.f * __builtin_amdgcn_rcpf(__expf(2.f * x) + 1.f);
}
__device__ __forceinline__ float dot2p(u32 w, u32 a, float acc) {
#ifdef HAS_FDOT2
  return __builtin_amdgcn_fdot2(__builtin_bit_cast(half2v, w),
                                __builtin_bit_cast(half2v, a), acc, false);
#else
  half2v hw = __builtin_bit_cast(half2v, w), ha = __builtin_bit_cast(half2v, a);
  acc = fmaf((float)hw.x, (float)ha.x, acc);
  return fmaf((float)hw.y, (float)ha.y, acc);
#endif
}
__device__ __forceinline__ int dot4i(u32 w, u32 a, int acc) {
#ifdef HAS_SDOT4
  return __builtin_amdgcn_sdot4((int)w, (int)a, acc, false);
#else
  acc += (((int)(w << 24)) >> 24) * (((int)(a << 24)) >> 24);
  acc += (((int)(w << 16)) >> 24) * (((int)(a << 16)) >> 24);
  acc += (((int)(w << 8))  >> 24) * (((int)(a << 8))  >> 24);
  acc += (((int)w) >> 24)         * (((int)a) >> 24);
  return acc;
#endif
}
__device__ __forceinline__ u32 packf16(float x, float y) {
  half2v h; h.x = (_Float16)x; h.y = (_Float16)y;
  return __builtin_bit_cast(u32, h);
}
__device__ __forceinline__ u16 f16b(float x) {
  _Float16 h = (_Float16)x;
  return __builtin_bit_cast(u16, h);
}

// ---- ws layout (bytes, 256-aligned); same sizes, GATE-INTERLEAVED content ----
#define O_WZX  256                       // wzxG: [k2][u] uint4 (4 gates f16-pairs): 32*2048 u32
#define O_WZ8  (O_WZX + 262144)          // wzG: [q][u] uint4 (4 gates i8-quads): 128*2048 u32
#define O_SWZ  (O_WZ8 + 1048576)         // swzG: [u][g] f32[2048]
#define O_BB8  (O_SWZ + 8192)            // bb i8 quads: 144*128 u32 (unchanged)
#define O_SBB  (O_BB8 + 73728)           // bb weight scales: f32[128]
#define O_FF8  (O_SBB + 512)             // ffG: [l][u] uint4 (4 mats): 32*2048 u32
#define O_SFF  (O_FF8 + 262144)          // sffG: [u][mat] f32[2048]
#define O_BIF  (O_SFF + 8192)            // bi f32[2048]
#define O_FFB  (O_BIF + 8192)            // ff biases f32[4*512]
#define O_BBBF (O_FFB + 8192)            // bbb f32[128]
#define O_HWP  (O_BBBF + 512)            // head pairs u32[512]
#define O_HBF  (O_HWP + 2048)            // hb f32[2]
#define WS_NEED ((u64)(O_HBF + 256))     // ~1.68 MB

// ---------------- dtype detection (validated rounds 3-8) ----------------
__global__ void detect_kernel(const u16* x, const u16* wi, const u16* wh, int* flag) {
  const int l = threadIdx.x;
  int cnt = (((x[2 * l] >> 7) & 0xFF) < 134)
          + (((wi[2 * l] >> 7) & 0xFF) < 134)
          + (((wh[2 * l] >> 7) & 0xFF) < 134);
#pragma unroll
  for (int off = 32; off > 0; off >>= 1) cnt += __shfl_down(cnt, off, 64);
  if (l == 0) *flag = (cnt >= 180) ? 1 : 0;
}

__device__ __forceinline__ float ldf(int f, const void* s, u32 i) {
  return f ? bf2f(((const u16*)s)[i]) : ((const float*)s)[i];
}

// ---- prep: Wz x-part f16 pairs, gate-interleaved ----
__global__ void pwzx_kernel(const void* Wi, const int* __restrict__ flag,
                            u32* __restrict__ wzxG) {
  const int o = blockIdx.x * 256 + threadIdx.x;   // z-row 0..2047
  const int k2 = blockIdx.y;
  const int f = *flag;
  const u32 i = (u32)o * DI + 2 * k2;
  wzxG[(u32)k2 * GZ + (((u32)(o & 511)) << 2) + (o >> 9)] =
      packf16(ldf(f, Wi, i), ldf(f, Wi, i + 1));
}

// ---- prep: Wz h-part -> i8, gate-interleaved; per-row scale ----
__global__ void qwz_kernel(const void* Wh, const int* __restrict__ flag,
                           u32* __restrict__ wzG, float* __restrict__ swzG) {
  const int o = blockIdx.x;       // z-row 0..2047
  const int l = threadIdx.x;
  const int f = *flag;
  float w[8]; float mx = 0.f;
#pragma unroll
  for (int qq = 0; qq < 2; ++qq) {
    const int q = l + 64 * qq;
#pragma unroll
    for (int e = 0; e < 4; ++e) {
      const float v = ldf(f, Wh, (u32)o * DH + 4 * q + e);
      w[qq * 4 + e] = v; mx = fmaxf(mx, fabsf(v));
    }
  }
#pragma unroll
  for (int off = 32; off > 0; off >>= 1) mx = fmaxf(mx, __shfl_xor(mx, off, 64));
  mx = fmaxf(mx, 1e-20f);
  const float inv = 127.f / mx;
  if (l == 0) swzG[(((u32)(o & 511)) << 2) + (o >> 9)] = mx / (127.f * 127.f);
#pragma unroll
  for (int qq = 0; qq < 2; ++qq) {
    const int q = l + 64 * qq;
    u32 p = 0;
#pragma unroll
    for (int e = 0; e < 4; ++e) {
      int b = (int)rintf(w[qq * 4 + e] * inv);
      b = b > 127 ? 127 : (b < -127 ? -127 : b);
      p |= ((u32)(b & 0xff)) << (8 * e);
    }
    wzG[(u32)q * GZ + (((u32)(o & 511)) << 2) + (o >> 9)] = p;
  }
}

// ---- prep: backbone -> i8, per-output scale (layout unchanged) ----
__global__ void qbb_kernel(const void* bb, const int* __restrict__ flag,
                           u32* __restrict__ bb8, float* __restrict__ sbb) {
  const int m = blockIdx.x;      // 0..127
  const int l = threadIdx.x;     // 0..63
  const int f = *flag;
  float mx = 0.f;
#pragma unroll
  for (int q = 0; q < 9; ++q)
    mx = fmaxf(mx, fabsf(ldf(f, bb, (u32)m * KZ + l + 64 * q)));
#pragma unroll
  for (int off = 32; off > 0; off >>= 1) mx = fmaxf(mx, __shfl_xor(mx, off, 64));
  mx = fmaxf(mx, 1e-20f);
  const float inv = 127.f / mx;
  if (l == 0) sbb[m] = mx / 127.f;
  for (int k4 = l; k4 < 144; k4 += 64) {
    u32 p = 0;
#pragma unroll
    for (int e = 0; e < 4; ++e) {
      int b = (int)rintf(ldf(f, bb, (u32)m * KZ + 4 * k4 + e) * inv);
      b = b > 127 ? 127 : (b < -127 ? -127 : b);
      p |= ((u32)(b & 0xff)) << (8 * e);
    }
    bb8[(u32)k4 * DB + m] = p;
  }
}

// ---- prep: ff -> i8, mat-interleaved uint4 per (l, unit) ----
__global__ void qff_kernel(const void* f1, const void* f2, const void* ta,
                           const void* tb, const int* __restrict__ flag,
                           u32* __restrict__ ffG, float* __restrict__ sffG) {
  const int o = blockIdx.x;      // 0..511 (unit)
  const int mat = blockIdx.y;    // 0..3
  const int l = threadIdx.x;     // 0..31 (k4)
  const void* s = (mat == 0) ? f1 : (mat == 1) ? f2 : (mat == 2) ? ta : tb;
  const int f = *flag;
  float w[4]; float mx = 0.f;
#pragma unroll
  for (int e = 0; e < 4; ++e) {
    w[e] = ldf(f, s, (u32)o * DB + 4 * l + e);
    mx = fmaxf(mx, fabsf(w[e]));
  }
#pragma unroll
  for (int off = 16; off > 0; off >>= 1) mx = fmaxf(mx, __shfl_xor(mx, off, 32));
  mx = fmaxf(mx, 1e-20f);
  const float inv = 127.f / mx;
  if (l == 0) sffG[((u32)o << 2) + mat] = (mx / 127.f) * (1.7159f / 127.f);
  u32 p = 0;
#pragma unroll
  for (int e = 0; e < 4; ++e) {
    int b = (int)rintf(w[e] * inv);
    b = b > 127 ? 127 : (b < -127 ? -127 : b);
    p |= ((u32)(b & 0xff)) << (8 * e);
  }
  ffG[(((u32)l * 512 + o) << 2) + mat] = p;
}

__global__ void psmall_kernel(const void* bi_s, const void* f1b_s, const void* f2b_s,
                              const void* tab_s, const void* tbb_s, const void* bbb_s,
                              const void* hw_s, const void* hb_s,
                              const int* __restrict__ flag,
                              float* __restrict__ bif, float* __restrict__ ffb,
                              float* __restrict__ bbbf, u32* __restrict__ hwp,
                              float* __restrict__ hbf) {
  const int f = *flag;
  for (int i = threadIdx.x; i < 2048; i += 1024) {
    bif[i] = ldf(f, bi_s, i);
    if (i < 512) {
      ffb[i]        = ldf(f, f1b_s, i);
      ffb[512 + i]  = ldf(f, f2b_s, i);
      ffb[1024 + i] = ldf(f, tab_s, i);
      ffb[1536 + i] = ldf(f, tbb_s, i);
      const int w = i >> 8, pr = i & 255;
      hwp[i] = packf16(ldf(f, hw_s, w * DH + 2 * pr), ldf(f, hw_s, w * DH + 2 * pr + 1));
    }
    if (i < 128) bbbf[i] = ldf(f, bbb_s, i);
    if (i < 2)   hbf[i] = ldf(f, hb_s, i);
  }
}

// ---- scan15: gate-interleaved fused phases; 3 barriers/step ----
// Thread u<512 owns hidden unit u end-to-end: Z(4 gates, both rows) -> gates
// -> c,h_lstm local (no zred, no gates barrier); ff(4 mats) -> combine local
// (no zff). bb+F on 128 threads from LDS bbL (no bbred). Int sums exact;
// float reassociation only (tolerance >=0.0083 proven in r6).
__global__ __launch_bounds__(1024, 1)
void scan15(const void* __restrict__ xraw, const int* __restrict__ flagp,
            const u32* __restrict__ wzxG, const u32* __restrict__ wzG,
            const float* __restrict__ swzG,
            const u32* __restrict__ bb8, const float* __restrict__ sbb,
            const u32* __restrict__ ffG, const float* __restrict__ sffG,
            const float* __restrict__ bif, const float* __restrict__ ffbv,
            const float* __restrict__ bbbf, const u32* __restrict__ hwp,
            const float* __restrict__ hbf, float* __restrict__ out)
{
  __shared__ __align__(16) u32   xf16q[64];      // x(t) f16 pairs [k2][row]
  __shared__ __align__(16) u32   ah8q[256];      // h(t-1) i8 quads [k4][row]
  __shared__ __align__(16) u32   hfR[512];       // h(t) f16 [row][unit] (u16 view)
  __shared__ __align__(16) u32   vcat8[288];     // [x|h_lstm] i8 quads [k4][row]
  __shared__ __align__(16) float sxq[2];         // per-row x quant scale
  __shared__ __align__(16) u32   Fq8[64];        // F i8 quads [k4][row]
  __shared__ __align__(16) u32   bbL[144 * DB];  // bb weights resident: 72 KB

  const int j = threadIdx.x;
  const int b = blockIdx.x;          // rows 2b, 2b+1
  const int bf16in = *flagp;
  const int u = j & 511;

  // persistent per-unit state (j<512)
  float c0 = 0.f, c1 = 0.f;
  float bgi = 0, bgg = 0, bgf = 0, bgo = 0, cb1 = 0, cb2 = 0, cba = 0, cbb = 0;
  float4 zscl = make_float4(0, 0, 0, 0), sfv = make_float4(0, 0, 0, 0);
  if (j < 512) {
    bgi = bif[0 * DH + u]; bgg = bif[1 * DH + u];
    bgf = bif[2 * DH + u]; bgo = bif[3 * DH + u];
    cb1 = ffbv[0 * DH + u]; cb2 = ffbv[1 * DH + u];
    cba = ffbv[2 * DH + u]; cbb = ffbv[3 * DH + u];
    zscl = *(const float4*)(swzG + 4 * u);
    sfv  = *(const float4*)(sffG + 4 * u);
  }
  float sbbr = 0.f, bbr = 0.f;
  if (j < 128) { sbbr = sbb[j]; bbr = bbbf[j]; }
  u32 hwreg[4] = {0, 0, 0, 0}; float hbr = 0.f;
  int hrow = 0, hw_ = 0, hl = 0;
  if (j >= 512 && j < 768) {
    const int jj = j - 512;
    hrow = jj >> 7; hw_ = (jj >> 6) & 1; hl = jj & 63;
#pragma unroll
    for (int i = 0; i < 4; ++i) hwreg[i] = hwp[hw_ * 256 + hl + 64 * i];
    hbr = hbf[hw_];
  }
  const float C127 = 1.f / 127.f;

  // ---- bb weights resident in LDS (once) ----
  for (int i = j; i < 144 * DB; i += 1024) bbL[i] = bb8[i];

  // ---- preamble: h0 = 0; stage x(0) ----
  if (j < 512) { hfR[j] = 0u; if (j < 256) ah8q[j] = 0u; }
  if (j >= 512 && j < 576) {
    const int i = j - 512, xr = i >> 5, k2 = i & 31;
    const size_t xi = ((size_t)(2 * b + xr) * TT + 0) * 32 + k2;
    float a, bb_;
    if (bf16in) {
      const u32 w = ((const u32*)xraw)[xi];
      a = bf2f((u16)(w & 0xffffu)); bb_ = bf2f((u16)(w >> 16));
    } else {
      const float2 v = ((const float2*)xraw)[xi];
      a = v.x; bb_ = v.y;
    }
    xf16q[k2 * 2 + xr] = packf16(a, bb_);
    float m = fmaxf(fabsf(a), fabsf(bb_));
#pragma unroll
    for (int off = 16; off > 0; off >>= 1) m = fmaxf(m, __shfl_xor(m, off, 32));
    m = fmaxf(m, 1e-20f);
    if (k2 == 0) sxq[xr] = m * C127;
    const float inv = 127.f / m;
    const int q0 = (int)rintf(a * inv), q1 = (int)rintf(bb_ * inv);
    ((u16*)vcat8)[((k2 >> 1) * 2 + xr) * 2 + (k2 & 1)] =
        (u16)((q0 & 0xff) | ((q1 & 0xff) << 8));
  }
  __syncthreads();

  for (int t = 0; t < TT; ++t) {
    // ---- phase 1: Z (all 4 gates, both rows) + LSTM gates, fused ----
    if (j < 512) {
      float xi0 = 0, xg0 = 0, xf0 = 0, xo0 = 0, xi1 = 0, xg1 = 0, xf1 = 0, xo1 = 0;
      const u32* wpx = wzxG + 4 * u;
#pragma unroll 8
      for (int k2 = 0; k2 < 32; ++k2) {
        const uint4 w = *(const uint4*)wpx; wpx += GZ;
        const u32 a0 = xf16q[k2 * 2 + 0], a1 = xf16q[k2 * 2 + 1];
        xi0 = dot2p(w.x, a0, xi0); xg0 = dot2p(w.y, a0, xg0);
        xf0 = dot2p(w.z, a0, xf0); xo0 = dot2p(w.w, a0, xo0);
        xi1 = dot2p(w.x, a1, xi1); xg1 = dot2p(w.y, a1, xg1);
        xf1 = dot2p(w.z, a1, xf1); xo1 = dot2p(w.w, a1, xo1);
      }
      int ii0 = 0, ig0 = 0, if0 = 0, io0 = 0, ii1 = 0, ig1 = 0, if1 = 0, io1 = 0;
      const u32* wph = wzG + 4 * u;
#pragma unroll 8
      for (int q = 0; q < 128; ++q) {
        const uint4 w = *(const uint4*)wph; wph += GZ;
        const u32 a0 = ah8q[q * 2 + 0], a1 = ah8q[q * 2 + 1];
        ii0 = dot4i(w.x, a0, ii0); ig0 = dot4i(w.y, a0, ig0);
        if0 = dot4i(w.z, a0, if0); io0 = dot4i(w.w, a0, io0);
        ii1 = dot4i(w.x, a1, ii1); ig1 = dot4i(w.y, a1, ig1);
        if1 = dot4i(w.z, a1, if1); io1 = dot4i(w.w, a1, io1);
      }
      const float zi0 = bgi + xi0 + zscl.x * (float)ii0;
      const float zg0 = bgg + xg0 + zscl.y * (float)ig0;
      const float zf0 = bgf + xf0 + zscl.z * (float)if0;
      const float zo0 = bgo + xo0 + zscl.w * (float)io0;
      const float zi1 = bgi + xi1 + zscl.x * (float)ii1;
      const float zg1 = bgg + xg1 + zscl.y * (float)ig1;
      const float zf1 = bgf + xf1 + zscl.z * (float)if1;
      const float zo1 = bgo + xo1 + zscl.w * (float)io1;
      c0 = fmaf(c0, fsig(zf0 + 1.f), ftanh(zi0) * fsig(zg0));
      c1 = fmaf(c1, fsig(zf1 + 1.f), ftanh(zi1) * fsig(zg1));
      const float hl0 = ftanh(c0) * fsig(zo0);
      const float hl1 = ftanh(c1) * fsig(zo1);
      const int q0 = (int)rintf(hl0 * 127.f), q1 = (int)rintf(hl1 * 127.f);
      ((u8*)vcat8)[((16 + (u >> 2)) * 2 + 0) * 4 + (u & 3)] = (u8)(q0 & 0xff);
      ((u8*)vcat8)[((16 + (u >> 2)) * 2 + 1) * 4 + (u & 3)] = (u8)(q1 & 0xff);
    }
    __syncthreads();                                   // B1: h_lstm ready

    // ---- phase 2: backbone + F + quantize, fused (128 threads) ----
    if (j < 128) {
      int ax0 = 0, ax1 = 0, ah0 = 0, ah1 = 0;
      const u32* bp = bbL + j;
#pragma unroll
      for (int q = 0; q < 16; ++q) {
        const u32 w = bp[q * DB];
        ax0 = dot4i(w, vcat8[q * 2 + 0], ax0);
        ax1 = dot4i(w, vcat8[q * 2 + 1], ax1);
      }
#pragma unroll 16
      for (int q = 16; q < 144; ++q) {
        const u32 w = bp[q * DB];
        ah0 = dot4i(w, vcat8[q * 2 + 0], ah0);
        ah1 = dot4i(w, vcat8[q * 2 + 1], ah1);
      }
      const float r0 = bbr + sbbr * (sxq[0] * (float)ax0 + C127 * (float)ah0);
      const float r1 = bbr + sbbr * (sxq[1] * (float)ax1 + C127 * (float)ah1);
      const float F0 = 1.7159f * ftanh(0.666f * r0);
      const float F1 = 1.7159f * ftanh(0.666f * r1);
      const int q0 = (int)rintf(F0 * (127.f / 1.7159f));
      const int q1 = (int)rintf(F1 * (127.f / 1.7159f));
      ((u8*)Fq8)[((j >> 2) * 2 + 0) * 4 + (j & 3)] = (u8)(q0 & 0xff);
      ((u8*)Fq8)[((j >> 2) * 2 + 1) * 4 + (j & 3)] = (u8)(q1 & 0xff);
    }
    __syncthreads();                                   // B2: F ready

    // ---- phase 3: ff (4 mats) + combine fused || stage x(t+1) ----
    if (j < 512) {
      int a10 = 0, a20 = 0, aa0 = 0, ab0 = 0, a11 = 0, a21 = 0, aa1 = 0, ab1 = 0;
      const u32* fw = ffG + 4 * u;
#pragma unroll 8
      for (int l = 0; l < 32; ++l) {
        const uint4 w = *(const uint4*)fw; fw += GZ;
        const u32 F0v = Fq8[l * 2 + 0], F1v = Fq8[l * 2 + 1];
        a10 = dot4i(w.x, F0v, a10); a20 = dot4i(w.y, F0v, a20);
        aa0 = dot4i(w.z, F0v, aa0); ab0 = dot4i(w.w, F0v, ab0);
        a11 = dot4i(w.x, F1v, a11); a21 = dot4i(w.y, F1v, a21);
        aa1 = dot4i(w.z, F1v, aa1); ab1 = dot4i(w.w, F1v, ab1);
      }
      const float z10 = sfv.x * (float)a10 + cb1, z20 = sfv.y * (float)a20 + cb2;
      const float za0 = sfv.z * (float)aa0 + cba, zb0 = sfv.w * (float)ab0 + cbb;
      const float z11 = sfv.x * (float)a11 + cb1, z21 = sfv.y * (float)a21 + cb2;
      const float za1 = sfv.z * (float)aa1 + cba, zb1 = sfv.w * (float)ab1 + cbb;
      const float ti0 = fsig(za0 + zb0), ti1 = fsig(za1 + zb1);
      const float hn0 = fmaf(ftanh(z10), 1.f - ti0, ti0 * ftanh(z20));
      const float hn1 = fmaf(ftanh(z11), 1.f - ti1, ti1 * ftanh(z21));
      ((u16*)hfR)[u] = f16b(hn0);
      ((u16*)hfR)[512 + u] = f16b(hn1);
      const int q0 = (int)rintf(hn0 * 127.f), q1 = (int)rintf(hn1 * 127.f);
      ((u8*)ah8q)[((u >> 2) * 2 + 0) * 4 + (u & 3)] = (u8)(q0 & 0xff);
      ((u8*)ah8q)[((u >> 2) * 2 + 1) * 4 + (u & 3)] = (u8)(q1 & 0xff);
      if (t == TT - 1) {
        out[(size_t)NB * TT * 2 + (size_t)(2 * b + 0) * DH + u] = hn0;
        out[(size_t)NB * TT * 2 + (size_t)(2 * b + 1) * DH + u] = hn1;
      }
    } else if (j < 576 && t + 1 < TT) {
      const int i = j - 512, xr = i >> 5, k2 = i & 31;
      const size_t xi = ((size_t)(2 * b + xr) * TT + (t + 1)) * 32 + k2;
      float a, bb_;
      if (bf16in) {
        const u32 w = ((const u32*)xraw)[xi];
        a = bf2f((u16)(w & 0xffffu)); bb_ = bf2f((u16)(w >> 16));
      } else {
        const float2 v = ((const float2*)xraw)[xi];
        a = v.x; bb_ = v.y;
      }
      xf16q[k2 * 2 + xr] = packf16(a, bb_);
      float m = fmaxf(fabsf(a), fabsf(bb_));
#pragma unroll
      for (int off = 16; off > 0; off >>= 1) m = fmaxf(m, __shfl_xor(m, off, 32));
      m = fmaxf(m, 1e-20f);
      if (k2 == 0) sxq[xr] = m * C127;
      const float inv = 127.f / m;
      const int q0 = (int)rintf(a * inv), q1 = (int)rintf(bb_ * inv);
      ((u16*)vcat8)[((k2 >> 1) * 2 + xr) * 2 + (k2 & 1)] =
          (u16)((q0 & 0xff) | ((q1 & 0xff) << 8));
    }
    __syncthreads();                                   // B3: h_new + x(t+1) ready

    // ---- phase 4: head (waves 8-11), runs in the shadow of next Z ----
    if (j >= 512 && j < 768) {
      float acc = 0.f;
#pragma unroll
      for (int i = 0; i < 4; ++i)
        acc = dot2p(hwreg[i], hfR[hrow * 256 + hl + 64 * i], acc);
#pragma unroll
      for (int off = 32; off > 0; off >>= 1) acc += __shfl_down(acc, off, 64);
      if (hl == 0) out[((size_t)(2 * b + hrow) * TT + t) * 2 + hw_] = acc + hbr;
    }
  }
}

// ---------------- fallback (round-3 verified, bf16 d_in, small ws) ----------------
__device__ __forceinline__ void fma8(float& acc, const uint4 u, const float* v) {
  union { u32 i; float f; } tt;
  tt.i = u.x << 16;          acc = fmaf(tt.f, v[0], acc);
  tt.i = u.x & 0xffff0000u;  acc = fmaf(tt.f, v[1], acc);
  tt.i = u.y << 16;          acc = fmaf(tt.f, v[2], acc);
  tt.i = u.y & 0xffff0000u;  acc = fmaf(tt.f, v[3], acc);
  tt.i = u.z << 16;          acc = fmaf(tt.f, v[4], acc);
  tt.i = u.z & 0xffff0000u;  acc = fmaf(tt.f, v[5], acc);
  tt.i = u.w << 16;          acc = fmaf(tt.f, v[6], acc);
  tt.i = u.w & 0xffff0000u;  acc = fmaf(tt.f, v[7], acc);
}
__global__ __launch_bounds__(256, 1)
void fb_scan(const u16* __restrict__ x,   const u16* __restrict__ Wi,
             const u16* __restrict__ bi,  const u16* __restrict__ Wh,
             const u16* __restrict__ bbW, const u16* __restrict__ bbb,
             const u16* __restrict__ f1W, const u16* __restrict__ f1b,
             const u16* __restrict__ f2W, const u16* __restrict__ f2b,
             const u16* __restrict__ taW, const u16* __restrict__ tab,
             const u16* __restrict__ tbW, const u16* __restrict__ tbb,
             const u16* __restrict__ hW,  const u16* __restrict__ hb,
             float* __restrict__ out)
{
  __shared__ __align__(16) float vcat[DI + DH];
  __shared__ __align__(16) float Fb2[DB];
  __shared__ __align__(16) float fpart[256];
  __shared__ __align__(16) float hprev[DH];
  const int j = threadIdx.x, b = blockIdx.x;
  const int u0 = j, u1 = j + 256;
  float bi_r[8];
#pragma unroll
  for (int k = 0; k < 8; ++k) bi_r[k] = bf2f(bi[j + 256 * k]);
  const float b_f1_0 = bf2f(f1b[u0]), b_f1_1 = bf2f(f1b[u1]);
  const float b_f2_0 = bf2f(f2b[u0]), b_f2_1 = bf2f(f2b[u1]);
  const float b_ta_0 = bf2f(tab[u0]), b_ta_1 = bf2f(tab[u1]);
  const float b_tb_0 = bf2f(tbb[u0]), b_tb_1 = bf2f(tbb[u1]);
  const float b_bb = (j < DB) ? bf2f(bbb[j]) : 0.f;
  float hwr[8]; float hbr = 0.f;
  if (j < 128) {
    const int w = j >> 6, l = j & 63;
#pragma unroll
    for (int q = 0; q < 8; ++q) hwr[q] = bf2f(hW[w * DH + q * 64 + l]);
    hbr = bf2f(hb[w]);
  }
  float c0 = 0.f, c1 = 0.f;
  hprev[u0] = 0.f; hprev[u1] = 0.f;
  const u16* xp = x + (size_t)b * TT * DI;
  __syncthreads();
  for (int t = 0; t < TT; ++t) {
    if (j < DI) vcat[j] = bf2f(xp[t * DI + j]);
    __syncthreads();
    float a[8];
#pragma unroll
    for (int k = 0; k < 8; ++k) a[k] = bi_r[k];
#pragma unroll
    for (int r = 0; r < 8; ++r) {
      const u16* wr = Wi + ((size_t)(j + 256 * r)) * DI;
      float acc = a[r];
#pragma unroll
      for (int kk = 0; kk < DI; kk += 8) fma8(acc, *(const uint4*)(wr + kk), vcat + kk);
      a[r] = acc;
    }
#pragma unroll 1
    for (int kb = 0; kb < DH; kb += 64) {
      float hreg[64];
#pragma unroll
      for (int q = 0; q < 16; ++q)
        *(float4*)(hreg + 4 * q) = *(const float4*)(hprev + kb + 4 * q);
#pragma unroll
      for (int r = 0; r < 8; ++r) {
        const u16* wr = Wh + ((size_t)(j + 256 * r)) * DH + kb;
        float acc = a[r];
#pragma unroll
        for (int cc = 0; cc < 8; ++cc) fma8(acc, *(const uint4*)(wr + 8 * cc), hreg + 8 * cc);
        a[r] = acc;
      }
    }
    {
      const float cn0 = fmaf(c0, fsig(a[4] + 1.f), ftanh(a[0]) * fsig(a[2]));
      const float cn1 = fmaf(c1, fsig(a[5] + 1.f), ftanh(a[1]) * fsig(a[3]));
      c0 = cn0; c1 = cn1;
      vcat[DI + u0] = ftanh(cn0) * fsig(a[6]);
      vcat[DI + u1] = ftanh(cn1) * fsig(a[7]);
    }
    __syncthreads();
    {
      const int mm = j & (DB - 1), pp = j >> 7;
      const u16* br = bbW + (size_t)mm * KZ + pp * 288;
      const float* vs = vcat + pp * 288;
      float s0 = 0.f, s1 = 0.f, s2v = 0.f, s3 = 0.f;
#pragma unroll
      for (int kk = 0; kk < 288; kk += 32) {
        fma8(s0, *(const uint4*)(br + kk), vs + kk);
        fma8(s1, *(const uint4*)(br + kk + 8), vs + kk + 8);
        fma8(s2v, *(const uint4*)(br + kk + 16), vs + kk + 16);
        fma8(s3, *(const uint4*)(br + kk + 24), vs + kk + 24);
      }
      fpart[j] = (s0 + s1) + (s2v + s3);
    }
    __syncthreads();
    if (j < DB) Fb2[j] = 1.7159f * ftanh(0.666f * (b_bb + fpart[j] + fpart[j + DB]));
    __syncthreads();
    {
      float Fr[DB];
#pragma unroll
      for (int q = 0; q < 32; ++q) *(float4*)(Fr + 4 * q) = *(const float4*)(Fb2 + 4 * q);
      const u16* rp[8] = {
        f1W + (size_t)u0 * DB, f1W + (size_t)u1 * DB,
        f2W + (size_t)u0 * DB, f2W + (size_t)u1 * DB,
        taW + (size_t)u0 * DB, taW + (size_t)u1 * DB,
        tbW + (size_t)u0 * DB, tbW + (size_t)u1 * DB };
      float sacc[8] = { b_f1_0, b_f1_1, b_f2_0, b_f2_1, b_ta_0, b_ta_1, b_tb_0, b_tb_1 };
#pragma unroll
      for (int rr = 0; rr < 8; ++rr) {
        float acc = sacc[rr];
        const u16* r = rp[rr];
#pragma unroll
        for (int kk = 0; kk < DB; kk += 8) fma8(acc, *(const uint4*)(r + kk), Fr + kk);
        sacc[rr] = acc;
      }
      const float ti0 = fsig(sacc[4] + sacc[6]);
      const float ti1 = fsig(sacc[5] + sacc[7]);
      hprev[u0] = fmaf(ftanh(sacc[0]), 1.f - ti0, ti0 * ftanh(sacc[2]));
      hprev[u1] = fmaf(ftanh(sacc[1]), 1.f - ti1, ti1 * ftanh(sacc[3]));
    }
    __syncthreads();
    if (j < 128) {
      const int l = j & 63;
      float acc = 0.f;
#pragma unroll
      for (int q = 0; q < 8; ++q) acc = fmaf(hprev[q * 64 + l], hwr[q], acc);
#pragma unroll
      for (int off = 32; off > 0; off >>= 1) acc += __shfl_down(acc, off, 64);
      if (l == 0) out[((size_t)b * TT + t) * 2 + (j >> 6)] = acc + hbr;
    }
  }
  out[(size_t)NB * TT * 2 + (size_t)b * DH + u0] = hprev[u0];
  out[(size_t)NB * TT * 2 + (size_t)b * DH + u1] = hprev[u1];
}

extern "C" void kernel_launch(void* const* d_in, const int* in_sizes, int n_in,
                              void* d_out, int out_size, void* d_ws, size_t ws_size,
                              hipStream_t stream) {
  (void)in_sizes; (void)n_in; (void)out_size;

  if (ws_size >= WS_NEED) {
    char* ws = (char*)d_ws;
    int* flag = (int*)ws;
    detect_kernel<<<dim3(1), dim3(64), 0, stream>>>(
        (const u16*)d_in[0], (const u16*)d_in[1], (const u16*)d_in[3], flag);
    pwzx_kernel<<<dim3(8, 32), dim3(256), 0, stream>>>(d_in[1], flag, (u32*)(ws + O_WZX));
    qwz_kernel<<<dim3(2048), dim3(64), 0, stream>>>(d_in[3], flag,
                                                    (u32*)(ws + O_WZ8), (float*)(ws + O_SWZ));
    qbb_kernel<<<dim3(128), dim3(64), 0, stream>>>(d_in[4], flag,
                                                   (u32*)(ws + O_BB8), (float*)(ws + O_SBB));
    qff_kernel<<<dim3(512, 4), dim3(32), 0, stream>>>(d_in[6], d_in[8], d_in[10],
                                                      d_in[12], flag,
                                                      (u32*)(ws + O_FF8), (float*)(ws + O_SFF));
    psmall_kernel<<<dim3(1), dim3(1024), 0, stream>>>(
        d_in[2], d_in[7], d_in[9], d_in[11], d_in[13], d_in[5], d_in[14], d_in[15],
        flag, (float*)(ws + O_BIF), (float*)(ws + O_FFB), (float*)(ws + O_BBBF),
        (u32*)(ws + O_HWP), (float*)(ws + O_HBF));

    scan15<<<dim3(64), dim3(1024), 0, stream>>>(
        d_in[0], flag,
        (const u32*)(ws + O_WZX), (const u32*)(ws + O_WZ8), (const float*)(ws + O_SWZ),
        (const u32*)(ws + O_BB8), (const float*)(ws + O_SBB),
        (const u32*)(ws + O_FF8), (const float*)(ws + O_SFF),
        (const float*)(ws + O_BIF), (const float*)(ws + O_FFB),
        (const float*)(ws + O_BBBF), (const u32*)(ws + O_HWP),
        (const float*)(ws + O_HBF), (float*)d_out);
  } else {
    fb_scan<<<dim3(NB), dim3(256), 0, stream>>>(
        (const u16*)d_in[0],  (const u16*)d_in[1],  (const u16*)d_in[2],
        (const u16*)d_in[3],  (const u16*)d_in[4],  (const u16*)d_in[5],
        (const u16*)d_in[6],  (const u16*)d_in[7],  (const u16*)d_in[8],
        (const u16*)d_in[9],  (const u16*)d_in[10], (const u16*)d_in[11],
        (const u16*)d_in[12], (const u16*)d_in[13], (const u16*)d_in[14],
        (const u16*)d_in[15], (float*)d_out);
  }
}